// Round 1
// baseline (3003.945 us; speedup 1.0000x reference)
//
#include <hip/hip_runtime.h>

typedef __attribute__((ext_vector_type(8))) short bf16x8;
typedef __attribute__((ext_vector_type(4))) float f32x4;

#define NEG_SLOPE 0.2f

__device__ __forceinline__ short f2bf(float f){
  unsigned u = __float_as_uint(f);
  u = (u + 0x7fffu + ((u >> 16) & 1u)) >> 16;   // RNE
  return (short)u;
}

// ---------------------------------------------------------------------------
// K0: pack W_typed fp32 [4,128,128] -> bf16 in MFMA B-fragment order.
// B matrix is [K=128, COL=512] with col = t*128 + o.  Fragment order:
// idx = ((ks*32 + ct)*64 + lane)*8 + j,  k = ks*32 + (lane>>4)*8 + j,
// col = ct*16 + (lane&15).
// ---------------------------------------------------------------------------
__global__ __launch_bounds__(256) void k_bprep(const float* __restrict__ W,
                                               short* __restrict__ Bfrag){
  int u = blockIdx.x * 256 + threadIdx.x;          // 0..65535
  int j = u & 7, lane = (u >> 3) & 63, ct = (u >> 9) & 31, ks = u >> 14;
  int k = ks * 32 + ((lane >> 4) << 3) + j;
  int col = (ct << 4) + (lane & 15);
  int t = col >> 7, o = col & 127;
  Bfrag[u] = f2bf(W[(t * 128 + k) * 128 + o]);
}

// ---------------------------------------------------------------------------
// K1: X0[n,:] = X[n,:] @ W[vtype[n]]  via MFMA 16x16x32 bf16.
// Block = 64 nodes (4 waves x 16 rows). Computes all 4 types (512 cols),
// stores only the node's type slice. A frags direct from global (each lane's
// frag is its own 8 contiguous floats). B staged per-32-K slab in LDS in
// fragment order (linear lane-order b128 -> conflict-free).
// ---------------------------------------------------------------------------
__global__ __launch_bounds__(256, 2) void k_gemm(const float* __restrict__ X,
    const int* __restrict__ vtype, const short* __restrict__ Bfrag,
    float* __restrict__ X0, int N){
  __shared__ short shB[32 * 64 * 8];               // 32KB
  const int tid = threadIdx.x, w = tid >> 6, lane = tid & 63;
  const int blockRow = blockIdx.x * 64;
  const int m = lane & 15, q = lane >> 4;
  const int node = blockRow + w * 16 + m;

  bf16x8 afrag[4];
  #pragma unroll
  for (int ks = 0; ks < 4; ++ks){
    bf16x8 f;
    if (node < N){
      const float4* src = (const float4*)(X + (size_t)node * 128 + ks * 32 + q * 8);
      float4 a = src[0], b = src[1];
      f[0]=f2bf(a.x); f[1]=f2bf(a.y); f[2]=f2bf(a.z); f[3]=f2bf(a.w);
      f[4]=f2bf(b.x); f[5]=f2bf(b.y); f[6]=f2bf(b.z); f[7]=f2bf(b.w);
    } else {
      #pragma unroll
      for (int z = 0; z < 8; ++z) f[z] = 0;
    }
    afrag[ks] = f;
  }

  f32x4 acc[32];
  #pragma unroll
  for (int ct = 0; ct < 32; ++ct){
    acc[ct][0]=0.f; acc[ct][1]=0.f; acc[ct][2]=0.f; acc[ct][3]=0.f;
  }

  for (int ks = 0; ks < 4; ++ks){
    __syncthreads();                               // protect shB reuse
    const bf16x8* src = (const bf16x8*)(Bfrag + (((size_t)ks * 32 + w * 8) * 64 + lane) * 8);
    bf16x8* dst = (bf16x8*)(shB + ((w * 8) * 64 + lane) * 8);
    #pragma unroll
    for (int ci = 0; ci < 8; ++ci) dst[ci * 64] = src[ci * 64];
    __syncthreads();
    bf16x8 af = afrag[ks];
    #pragma unroll
    for (int ct = 0; ct < 32; ++ct){
      bf16x8 bf = *(const bf16x8*)(shB + (ct * 64 + lane) * 8);
      acc[ct] = __builtin_amdgcn_mfma_f32_16x16x32_bf16(af, bf, acc[ct], 0, 0, 0);
    }
  }

  // C layout (m89-verified): col = lane&15, row = (lane>>4)*4 + reg
  const int col0 = lane & 15;
  #pragma unroll
  for (int r = 0; r < 4; ++r){
    int noder = blockRow + w * 16 + q * 4 + r;
    if (noder >= N) continue;
    int tt = vtype[noder];
    #pragma unroll
    for (int ct = 0; ct < 32; ++ct){
      if ((ct >> 3) == tt)
        X0[(size_t)noder * 128 + (ct & 7) * 16 + col0] = acc[ct][r];
    }
  }
}

// ---------------------------------------------------------------------------
// K2/K5: attention logits + exp + segment denominator.
// thread (i,h): d = <feat[rows[i], h*16:+16], att[seg_type[segs[i]], h, :]>
// pexp[i*8+h] = exp(leaky(d));  denom[segs[i]*8+h] += pexp
// (no max-subtraction: |logit| <~ 3, exp safe in fp32)
// ---------------------------------------------------------------------------
__global__ __launch_bounds__(256) void k_att(const float* __restrict__ feat,
    const float* __restrict__ att, const int* __restrict__ rows,
    const int* __restrict__ segs, const int* __restrict__ seg_type,
    float* __restrict__ pexp, float* __restrict__ denom, int NNZ){
  int g = blockIdx.x * 256 + threadIdx.x;
  int i = g >> 3, h = g & 7;
  if (i >= NNZ) return;
  int r = rows[i], s = segs[i], t = seg_type[s];
  const float4* xp = (const float4*)(feat + (size_t)r * 128 + h * 16);
  const float4* ap = (const float4*)(att + ((size_t)t * 8 + h) * 16);
  float d = 0.f;
  #pragma unroll
  for (int k = 0; k < 4; ++k){
    float4 x = xp[k], a = ap[k];
    d += x.x*a.x + x.y*a.y + x.z*a.z + x.w*a.w;
  }
  d = d > 0.f ? d : NEG_SLOPE * d;
  float ex = __expf(d);
  pexp[g] = ex;
  atomicAdd(denom + (size_t)s * 8 + h, ex);
}

// ---------------------------------------------------------------------------
// K3/K6: weighted scatter of feature rows into segment accumulators.
// thread (i, l): accum[segs[i], l*4:+4] += feat[rows[i], l*4:+4] * pexp[i,h]
// ---------------------------------------------------------------------------
__global__ __launch_bounds__(256) void k_scatter(const float* __restrict__ feat,
    const float* __restrict__ pexp, const int* __restrict__ rows,
    const int* __restrict__ segs, float* __restrict__ accum, int NNZ){
  int g = blockIdx.x * 256 + threadIdx.x;
  int i = g >> 5, l = g & 31;
  if (i >= NNZ) return;
  int r = rows[i], s = segs[i];
  float wgt = pexp[i * 8 + (l >> 2)];              // h = (l*4)>>4 = l>>2
  float4 x = *(const float4*)(feat + (size_t)r * 128 + l * 4);
  float* dst = accum + (size_t)s * 128 + l * 4;
  atomicAdd(dst + 0, x.x * wgt);
  atomicAdd(dst + 1, x.y * wgt);
  atomicAdd(dst + 2, x.z * wgt);
  atomicAdd(dst + 3, x.w * wgt);
}

// ---------------------------------------------------------------------------
// K4/K7: divide by (denom + eps), optional relu, in place.
// ---------------------------------------------------------------------------
__global__ __launch_bounds__(256) void k_fin(float* __restrict__ buf,
    const float* __restrict__ denom, int nseg, int do_relu){
  int g = blockIdx.x * 256 + threadIdx.x;
  int sidx = g >> 7, idx = g & 127;
  if (sidx >= nseg) return;
  float s = denom[(size_t)sidx * 8 + (idx >> 4)] + 1e-16f;
  float v = buf[(size_t)g] / s;
  if (do_relu) v = v > 0.f ? v : 0.f;
  buf[g] = v;
}

extern "C" void kernel_launch(void* const* d_in, const int* in_sizes, int n_in,
                              void* d_out, int out_size, void* d_ws, size_t ws_size,
                              hipStream_t stream){
  const float* X      = (const float*)d_in[0];
  const float* W      = (const float*)d_in[1];
  const float* att_e  = (const float*)d_in[2];
  const float* att_v  = (const float*)d_in[3];
  const int*   vertex = (const int*)d_in[4];
  const int*   edges  = (const int*)d_in[5];
  const int*   vtype  = (const int*)d_in[6];
  const int*   etype  = (const int*)d_in[7];
  float* out = (float*)d_out;
  const int N   = in_sizes[0] / 128;
  const int NNZ = in_sizes[4];
  const int E   = in_sizes[7];

  // workspace carve (all region sizes are 256B multiples for these shapes)
  char* wp = (char*)d_ws;
  float* s_e = (float*)wp; wp += (size_t)E * 8 * 4;     // edge denominators
  float* s_v = (float*)wp; wp += (size_t)N * 8 * 4;     // vertex denominators
  float* Xe  = (float*)wp; wp += (size_t)E * 128 * 4;   // edge accum -> edge features (in place)
  size_t zero_bytes = (size_t)(E * 8 + N * 8 + E * 128) * 4;
  float* X0  = (float*)wp; wp += (size_t)N * 128 * 4;   // projected node features
  short* Bfrag = (short*)wp; wp += (size_t)65536 * 2;   // W in bf16 frag order
  float* pq  = (float*)wp; wp += (size_t)NNZ * 8 * 4;   // exp(logits), reused both phases

  hipMemsetAsync(s_e, 0, zero_bytes, stream);                     // s_e, s_v, Xe
  hipMemsetAsync(out, 0, (size_t)out_size * 4, stream);           // vertex accum

  k_bprep<<<256, 256, 0, stream>>>(W, Bfrag);
  k_gemm<<<(N + 63) / 64, 256, 0, stream>>>(X, vtype, Bfrag, X0, N);

  // vertex -> edge
  k_att<<<(NNZ * 8 + 255) / 256, 256, 0, stream>>>(X0, att_e, vertex, edges, etype, pq, s_e, NNZ);
  k_scatter<<<(NNZ * 32 + 255) / 256, 256, 0, stream>>>(X0, pq, vertex, edges, Xe, NNZ);
  k_fin<<<(int)(((size_t)E * 128 + 255) / 256), 256, 0, stream>>>(Xe, s_e, E, 1);

  // edge -> vertex
  k_att<<<(NNZ * 8 + 255) / 256, 256, 0, stream>>>(Xe, att_v, edges, vertex, vtype, pq, s_v, NNZ);
  k_scatter<<<(NNZ * 32 + 255) / 256, 256, 0, stream>>>(Xe, pq, edges, vertex, out, NNZ);
  k_fin<<<(int)(((size_t)N * 128 + 255) / 256), 256, 0, stream>>>(out, s_v, N, 0);
}

// Round 2
// 525.508 us; speedup vs baseline: 5.7163x; 5.7163x over previous
//
#include <hip/hip_runtime.h>

typedef __attribute__((ext_vector_type(8))) short bf16x8;
typedef __attribute__((ext_vector_type(4))) float f32x4;

#define NEG_SLOPE 0.2f

__device__ __forceinline__ short f2bf(float f){
  unsigned u = __float_as_uint(f);
  u = (u + 0x7fffu + ((u >> 16) & 1u)) >> 16;   // RNE
  return (short)u;
}

// ---------------------------------------------------------------------------
// K0: pack W_typed fp32 [4,128,128] -> bf16 in MFMA B-fragment order.
// ---------------------------------------------------------------------------
__global__ __launch_bounds__(256) void k_bprep(const float* __restrict__ W,
                                               short* __restrict__ Bfrag){
  int u = blockIdx.x * 256 + threadIdx.x;          // 0..65535
  int j = u & 7, lane = (u >> 3) & 63, ct = (u >> 9) & 31, ks = u >> 14;
  int k = ks * 32 + ((lane >> 4) << 3) + j;
  int col = (ct << 4) + (lane & 15);
  int t = col >> 7, o = col & 127;
  Bfrag[u] = f2bf(W[(t * 128 + k) * 128 + o]);
}

// ---------------------------------------------------------------------------
// K1: X0[n,:] = X[n,:] @ W[vtype[n]]  via MFMA 16x16x32 bf16 (unchanged).
// ---------------------------------------------------------------------------
__global__ __launch_bounds__(256, 2) void k_gemm(const float* __restrict__ X,
    const int* __restrict__ vtype, const short* __restrict__ Bfrag,
    float* __restrict__ X0, int N){
  __shared__ short shB[32 * 64 * 8];               // 32KB
  const int tid = threadIdx.x, w = tid >> 6, lane = tid & 63;
  const int blockRow = blockIdx.x * 64;
  const int m = lane & 15, q = lane >> 4;
  const int node = blockRow + w * 16 + m;

  bf16x8 afrag[4];
  #pragma unroll
  for (int ks = 0; ks < 4; ++ks){
    bf16x8 f;
    if (node < N){
      const float4* src = (const float4*)(X + (size_t)node * 128 + ks * 32 + q * 8);
      float4 a = src[0], b = src[1];
      f[0]=f2bf(a.x); f[1]=f2bf(a.y); f[2]=f2bf(a.z); f[3]=f2bf(a.w);
      f[4]=f2bf(b.x); f[5]=f2bf(b.y); f[6]=f2bf(b.z); f[7]=f2bf(b.w);
    } else {
      #pragma unroll
      for (int z = 0; z < 8; ++z) f[z] = 0;
    }
    afrag[ks] = f;
  }

  f32x4 acc[32];
  #pragma unroll
  for (int ct = 0; ct < 32; ++ct){
    acc[ct][0]=0.f; acc[ct][1]=0.f; acc[ct][2]=0.f; acc[ct][3]=0.f;
  }

  for (int ks = 0; ks < 4; ++ks){
    __syncthreads();
    const bf16x8* src = (const bf16x8*)(Bfrag + (((size_t)ks * 32 + w * 8) * 64 + lane) * 8);
    bf16x8* dst = (bf16x8*)(shB + ((w * 8) * 64 + lane) * 8);
    #pragma unroll
    for (int ci = 0; ci < 8; ++ci) dst[ci * 64] = src[ci * 64];
    __syncthreads();
    bf16x8 af = afrag[ks];
    #pragma unroll
    for (int ct = 0; ct < 32; ++ct){
      bf16x8 bf = *(const bf16x8*)(shB + (ct * 64 + lane) * 8);
      acc[ct] = __builtin_amdgcn_mfma_f32_16x16x32_bf16(af, bf, acc[ct], 0, 0, 0);
    }
  }

  const int col0 = lane & 15;
  #pragma unroll
  for (int r = 0; r < 4; ++r){
    int noder = blockRow + w * 16 + q * 4 + r;
    if (noder >= N) continue;
    int tt = vtype[noder];
    #pragma unroll
    for (int ct = 0; ct < 32; ++ct){
      if ((ct >> 3) == tt)
        X0[(size_t)noder * 128 + (ct & 7) * 16 + col0] = acc[ct][r];
    }
  }
}

// ---------------------------------------------------------------------------
// CSR build: histogram -> scan (3 kernels) -> place
// ---------------------------------------------------------------------------
__global__ __launch_bounds__(256) void k_hist(const int* __restrict__ seg, int nnz,
                                              int* __restrict__ cnt){
  int i = blockIdx.x * 256 + threadIdx.x;
  if (i < nnz) atomicAdd(cnt + seg[i], 1);
}

__global__ __launch_bounds__(256) void k_scanA(const int* __restrict__ cnt, int S,
                                               int* __restrict__ bsum){
  __shared__ int sh[256];
  int base = blockIdx.x * 1024 + threadIdx.x * 4;
  int s = 0;
  #pragma unroll
  for (int k = 0; k < 4; ++k){ int idx = base + k; if (idx < S) s += cnt[idx]; }
  sh[threadIdx.x] = s; __syncthreads();
  for (int off = 128; off > 0; off >>= 1){
    if (threadIdx.x < off) sh[threadIdx.x] += sh[threadIdx.x + off];
    __syncthreads();
  }
  if (threadIdx.x == 0) bsum[blockIdx.x] = sh[0];
}

__global__ void k_scanB(int* bsum, int nb){
  if (threadIdx.x == 0 && blockIdx.x == 0){
    int run = 0;
    for (int b = 0; b < nb; ++b){ int v = bsum[b]; bsum[b] = run; run += v; }
  }
}

__global__ __launch_bounds__(256) void k_scanC(const int* __restrict__ cnt, int S,
    const int* __restrict__ bsum, int* __restrict__ offs, int* __restrict__ cursor){
  __shared__ int sh[256];
  int t = threadIdx.x;
  int base = blockIdx.x * 1024 + t * 4;
  int c[4]; int s = 0;
  #pragma unroll
  for (int k = 0; k < 4; ++k){ int idx = base + k; c[k] = (idx < S) ? cnt[idx] : 0; s += c[k]; }
  sh[t] = s; __syncthreads();
  for (int off = 1; off < 256; off <<= 1){
    int v = (t >= off) ? sh[t - off] : 0; __syncthreads();
    sh[t] += v; __syncthreads();
  }
  int run = bsum[blockIdx.x] + sh[t] - s;           // exclusive prefix for this thread
  #pragma unroll
  for (int k = 0; k < 4; ++k){
    int idx = base + k;
    if (idx < S){ offs[idx] = run; cursor[idx] = run; run += c[k]; }
  }
}

__global__ __launch_bounds__(256) void k_place(const int* __restrict__ seg,
    const int* __restrict__ other, int nnz, int* __restrict__ cursor,
    int* __restrict__ rows_sorted){
  int i = blockIdx.x * 256 + threadIdx.x;
  if (i < nnz){
    int pos = atomicAdd(cursor + seg[i], 1);
    rows_sorted[pos] = other[i];
  }
}

// ---------------------------------------------------------------------------
// K_seg: fused attention + softmax + weighted segment-sum. One wave/segment.
// Lane l owns output floats [2l, 2l+1] (h = l>>3). Per member row:
//   - coalesced 512B gather of feat row (kept in registers)
//   - logit via 8-lane shfl_xor reduce, leaky+exp
//   - accumulate numerator (regs) and denominator
// Epilogue: divide by (denom+eps), optional relu, single 512B store.
// ---------------------------------------------------------------------------
__global__ __launch_bounds__(256) void k_seg(const float* __restrict__ feat,
    const float* __restrict__ att, const int* __restrict__ rows_sorted,
    const int* __restrict__ offs, const int* __restrict__ cnt,
    const int* __restrict__ stype, float* __restrict__ outbuf,
    int S, int do_relu){
  int wid = threadIdx.x >> 6, lane = threadIdx.x & 63;
  int s = blockIdx.x * 4 + wid;
  if (s >= S) return;
  int t = stype[s];
  float a0 = att[t * 128 + 2 * lane], a1 = att[t * 128 + 2 * lane + 1];
  int start = offs[s], len = cnt[s];
  float denom = 0.f, acc0 = 0.f, acc1 = 0.f;

  float2 x = make_float2(0.f, 0.f);
  if (len > 0){
    int r0 = rows_sorted[start];
    x = *(const float2*)(feat + (size_t)r0 * 128 + 2 * lane);
  }
  for (int j = 0; j < len; ++j){
    float2 xc = x;
    if (j + 1 < len){                               // prefetch next row
      int rn = rows_sorted[start + j + 1];
      x = *(const float2*)(feat + (size_t)rn * 128 + 2 * lane);
    }
    float p = xc.x * a0 + xc.y * a1;
    p += __shfl_xor(p, 1);
    p += __shfl_xor(p, 2);
    p += __shfl_xor(p, 4);                          // full dot for head h=l>>3
    p = p > 0.f ? p : NEG_SLOPE * p;
    float w = __expf(p);
    denom += w; acc0 += w * xc.x; acc1 += w * xc.y;
  }
  float inv = 1.f / (denom + 1e-16f);
  float v0 = acc0 * inv, v1 = acc1 * inv;
  if (do_relu){ v0 = v0 > 0.f ? v0 : 0.f; v1 = v1 > 0.f ? v1 : 0.f; }
  *(float2*)(outbuf + (size_t)s * 128 + 2 * lane) = make_float2(v0, v1);
}

extern "C" void kernel_launch(void* const* d_in, const int* in_sizes, int n_in,
                              void* d_out, int out_size, void* d_ws, size_t ws_size,
                              hipStream_t stream){
  const float* X      = (const float*)d_in[0];
  const float* W      = (const float*)d_in[1];
  const float* att_e  = (const float*)d_in[2];
  const float* att_v  = (const float*)d_in[3];
  const int*   vertex = (const int*)d_in[4];
  const int*   edges  = (const int*)d_in[5];
  const int*   vtype  = (const int*)d_in[6];
  const int*   etype  = (const int*)d_in[7];
  float* out = (float*)d_out;
  const int N   = in_sizes[0] / 128;
  const int NNZ = in_sizes[4];
  const int E   = in_sizes[7];

  // workspace carve (all region sizes multiples of 16B)
  char* wp = (char*)d_ws;
  int* cnt_e    = (int*)wp; wp += (size_t)E * 4;      // |
  int* cnt_v    = (int*)wp; wp += (size_t)N * 4;      // | one contiguous memset
  int* offs_e   = (int*)wp; wp += (size_t)E * 4;
  int* cursor_e = (int*)wp; wp += (size_t)E * 4;
  int* offs_v   = (int*)wp; wp += (size_t)N * 4;
  int* cursor_v = (int*)wp; wp += (size_t)N * 4;
  int* bsum     = (int*)wp; wp += 512;                // <=128 block sums
  int* rows_e   = (int*)wp; wp += (size_t)NNZ * 4;    // vertex ids sorted by edge
  int* rows_v   = (int*)wp; wp += (size_t)NNZ * 4;    // edge ids sorted by vertex
  float* X0     = (float*)wp; wp += (size_t)N * 128 * 4;
  float* Xe     = (float*)wp; wp += (size_t)E * 128 * 4;
  short* Bfrag  = (short*)wp; wp += (size_t)65536 * 2;

  hipMemsetAsync(cnt_e, 0, (size_t)(E + N) * 4, stream);   // cnt_e + cnt_v

  // typed projection
  k_bprep<<<256, 256, 0, stream>>>(W, Bfrag);
  k_gemm<<<(N + 63) / 64, 256, 0, stream>>>(X, vtype, Bfrag, X0, N);

  const int nbI = (NNZ + 255) / 256;
  const int nbE = (E + 1023) / 1024, nbN = (N + 1023) / 1024;

  // CSR by edge (phase 1): rows_e[pos] = vertex[i], grouped by edges[i]
  k_hist <<<nbI, 256, 0, stream>>>(edges, NNZ, cnt_e);
  k_scanA<<<nbE, 256, 0, stream>>>(cnt_e, E, bsum);
  k_scanB<<<1, 64, 0, stream>>>(bsum, nbE);
  k_scanC<<<nbE, 256, 0, stream>>>(cnt_e, E, bsum, offs_e, cursor_e);
  k_place<<<nbI, 256, 0, stream>>>(edges, vertex, NNZ, cursor_e, rows_e);

  // CSR by vertex (phase 2): rows_v[pos] = edges[i], grouped by vertex[i]
  k_hist <<<nbI, 256, 0, stream>>>(vertex, NNZ, cnt_v);
  k_scanA<<<nbN, 256, 0, stream>>>(cnt_v, N, bsum);
  k_scanB<<<1, 64, 0, stream>>>(bsum, nbN);
  k_scanC<<<nbN, 256, 0, stream>>>(cnt_v, N, bsum, offs_v, cursor_v);
  k_place<<<nbI, 256, 0, stream>>>(vertex, edges, NNZ, cursor_v, rows_v);

  // phase 1: vertex -> edge (relu), phase 2: edge -> vertex
  k_seg<<<(E + 3) / 4, 256, 0, stream>>>(X0, att_e, rows_e, offs_e, cnt_e, etype, Xe, E, 1);
  k_seg<<<(N + 3) / 4, 256, 0, stream>>>(Xe, att_v, rows_v, offs_v, cnt_v, vtype, out, N, 0);
}

// Round 3
// 518.096 us; speedup vs baseline: 5.7980x; 1.0143x over previous
//
#include <hip/hip_runtime.h>

typedef __attribute__((ext_vector_type(8))) short bf16x8;
typedef __attribute__((ext_vector_type(4))) float f32x4;

#define NEG_SLOPE 0.2f

__device__ __forceinline__ unsigned short f2bf(float f){
  unsigned u = __float_as_uint(f);
  u = (u + 0x7fffu + ((u >> 16) & 1u)) >> 16;   // RNE
  return (unsigned short)u;
}
__device__ __forceinline__ float bflo(unsigned u){ return __uint_as_float(u << 16); }
__device__ __forceinline__ float bfhi(unsigned u){ return __uint_as_float(u & 0xffff0000u); }

// ---------------------------------------------------------------------------
// K0: pack W_typed fp32 [4,128,128] -> bf16 in MFMA B-fragment order.
// ---------------------------------------------------------------------------
__global__ __launch_bounds__(256) void k_bprep(const float* __restrict__ W,
                                               short* __restrict__ Bfrag){
  int u = blockIdx.x * 256 + threadIdx.x;          // 0..65535
  int j = u & 7, lane = (u >> 3) & 63, ct = (u >> 9) & 31, ks = u >> 14;
  int k = ks * 32 + ((lane >> 4) << 3) + j;
  int col = (ct << 4) + (lane & 15);
  int t = col >> 7, o = col & 127;
  Bfrag[u] = (short)f2bf(W[(t * 128 + k) * 128 + o]);
}

// ---------------------------------------------------------------------------
// K1: X0[n,:] = bf16( X[n,:] @ W[vtype[n]] )  via MFMA 16x16x32 bf16.
// ---------------------------------------------------------------------------
__global__ __launch_bounds__(256, 2) void k_gemm(const float* __restrict__ X,
    const int* __restrict__ vtype, const short* __restrict__ Bfrag,
    unsigned short* __restrict__ X0, int N){
  __shared__ short shB[32 * 64 * 8];               // 32KB
  const int tid = threadIdx.x, w = tid >> 6, lane = tid & 63;
  const int blockRow = blockIdx.x * 64;
  const int m = lane & 15, q = lane >> 4;
  const int node = blockRow + w * 16 + m;

  bf16x8 afrag[4];
  #pragma unroll
  for (int ks = 0; ks < 4; ++ks){
    bf16x8 f;
    if (node < N){
      const float4* src = (const float4*)(X + (size_t)node * 128 + ks * 32 + q * 8);
      float4 a = src[0], b = src[1];
      f[0]=(short)f2bf(a.x); f[1]=(short)f2bf(a.y); f[2]=(short)f2bf(a.z); f[3]=(short)f2bf(a.w);
      f[4]=(short)f2bf(b.x); f[5]=(short)f2bf(b.y); f[6]=(short)f2bf(b.z); f[7]=(short)f2bf(b.w);
    } else {
      #pragma unroll
      for (int z = 0; z < 8; ++z) f[z] = 0;
    }
    afrag[ks] = f;
  }

  f32x4 acc[32];
  #pragma unroll
  for (int ct = 0; ct < 32; ++ct){
    acc[ct][0]=0.f; acc[ct][1]=0.f; acc[ct][2]=0.f; acc[ct][3]=0.f;
  }

  for (int ks = 0; ks < 4; ++ks){
    __syncthreads();
    const bf16x8* src = (const bf16x8*)(Bfrag + (((size_t)ks * 32 + w * 8) * 64 + lane) * 8);
    bf16x8* dst = (bf16x8*)(shB + ((w * 8) * 64 + lane) * 8);
    #pragma unroll
    for (int ci = 0; ci < 8; ++ci) dst[ci * 64] = src[ci * 64];
    __syncthreads();
    bf16x8 af = afrag[ks];
    #pragma unroll
    for (int ct = 0; ct < 32; ++ct){
      bf16x8 bf = *(const bf16x8*)(shB + (ct * 64 + lane) * 8);
      acc[ct] = __builtin_amdgcn_mfma_f32_16x16x32_bf16(af, bf, acc[ct], 0, 0, 0);
    }
  }

  const int col0 = lane & 15;
  #pragma unroll
  for (int r = 0; r < 4; ++r){
    int noder = blockRow + w * 16 + q * 4 + r;
    if (noder >= N) continue;
    int tt = vtype[noder];
    #pragma unroll
    for (int ct = 0; ct < 32; ++ct){
      if ((ct >> 3) == tt)
        X0[(size_t)noder * 128 + (ct & 7) * 16 + col0] = f2bf(acc[ct][r]);
    }
  }
}

// ---------------------------------------------------------------------------
// Unified CSR build over concatenated segment space [0,E) edges, [E,E+N) verts.
// cnt_e sums to NNZ, so edge-grouped entries land in rows[0,NNZ) and
// vertex-grouped in rows[NNZ,2*NNZ) automatically.
// ---------------------------------------------------------------------------
__global__ __launch_bounds__(256) void k_hist2(const int* __restrict__ edges,
    const int* __restrict__ vertex, int nnz, int* __restrict__ cnt, int E){
  int i = blockIdx.x * 256 + threadIdx.x;
  if (i < nnz){
    atomicAdd(cnt + edges[i], 1);
    atomicAdd(cnt + E + vertex[i], 1);
  }
}

__global__ __launch_bounds__(256) void k_scanA(const int* __restrict__ cnt, int S,
                                               int* __restrict__ bsum){
  __shared__ int sh[256];
  int base = blockIdx.x * 1024 + threadIdx.x * 4;
  int s = 0;
  #pragma unroll
  for (int k = 0; k < 4; ++k){ int idx = base + k; if (idx < S) s += cnt[idx]; }
  sh[threadIdx.x] = s; __syncthreads();
  for (int off = 128; off > 0; off >>= 1){
    if (threadIdx.x < off) sh[threadIdx.x] += sh[threadIdx.x + off];
    __syncthreads();
  }
  if (threadIdx.x == 0) bsum[blockIdx.x] = sh[0];
}

__global__ void k_scanB(int* bsum, int nb){
  if (threadIdx.x == 0 && blockIdx.x == 0){
    int run = 0;
    for (int b = 0; b < nb; ++b){ int v = bsum[b]; bsum[b] = run; run += v; }
  }
}

__global__ __launch_bounds__(256) void k_scanC(const int* __restrict__ cnt, int S,
    const int* __restrict__ bsum, int* __restrict__ offs, int* __restrict__ cursor){
  __shared__ int sh[256];
  int t = threadIdx.x;
  int base = blockIdx.x * 1024 + t * 4;
  int c[4]; int s = 0;
  #pragma unroll
  for (int k = 0; k < 4; ++k){ int idx = base + k; c[k] = (idx < S) ? cnt[idx] : 0; s += c[k]; }
  sh[t] = s; __syncthreads();
  for (int off = 1; off < 256; off <<= 1){
    int v = (t >= off) ? sh[t - off] : 0; __syncthreads();
    sh[t] += v; __syncthreads();
  }
  int run = bsum[blockIdx.x] + sh[t] - s;           // exclusive prefix for this thread
  #pragma unroll
  for (int k = 0; k < 4; ++k){
    int idx = base + k;
    if (idx < S){ offs[idx] = run; cursor[idx] = run; run += c[k]; }
  }
}

__global__ __launch_bounds__(256) void k_place2(const int* __restrict__ edges,
    const int* __restrict__ vertex, int nnz, int* __restrict__ cursor,
    int* __restrict__ rows, int E){
  int i = blockIdx.x * 256 + threadIdx.x;
  if (i < nnz){
    int e = edges[i], v = vertex[i];
    int pe = atomicAdd(cursor + e, 1);
    rows[pe] = v;
    int pv = atomicAdd(cursor + E + v, 1);
    rows[pv] = e;
  }
}

// ---------------------------------------------------------------------------
// K_seg: fused attention + softmax + weighted segment-sum. One wave/segment.
// Features stored bf16 (one 4B word = 2 elems per lane). 2-deep row pipeline.
// ---------------------------------------------------------------------------
template<int OUT_BF16, int DO_RELU>
__global__ __launch_bounds__(256) void k_seg(const unsigned* __restrict__ feat,
    const float* __restrict__ att, const int* __restrict__ rows_sorted,
    const int* __restrict__ offs, const int* __restrict__ cnt,
    const int* __restrict__ stype, void* __restrict__ outbuf, int S){
  int wid = threadIdx.x >> 6, lane = threadIdx.x & 63;
  int s = blockIdx.x * 4 + wid;
  if (s >= S) return;
  int t = stype[s];
  float a0 = att[t * 128 + 2 * lane], a1 = att[t * 128 + 2 * lane + 1];
  int start = offs[s], len = cnt[s];
  float denom = 0.f, acc0 = 0.f, acc1 = 0.f;

  unsigned u0 = 0, u1 = 0;
  if (len > 0) u0 = feat[(size_t)rows_sorted[start] * 64 + lane];
  if (len > 1) u1 = feat[(size_t)rows_sorted[start + 1] * 64 + lane];
  for (int j = 0; j < len; ++j){
    unsigned uc = u0; u0 = u1;
    if (j + 2 < len) u1 = feat[(size_t)rows_sorted[start + j + 2] * 64 + lane];
    float x0 = bflo(uc), x1 = bfhi(uc);
    float p = x0 * a0 + x1 * a1;
    p += __shfl_xor(p, 1);
    p += __shfl_xor(p, 2);
    p += __shfl_xor(p, 4);                          // full dot for head h=lane>>3
    p = p > 0.f ? p : NEG_SLOPE * p;
    float w = __expf(p);
    denom += w; acc0 += w * x0; acc1 += w * x1;
  }
  float inv = 1.f / (denom + 1e-16f);
  float v0 = acc0 * inv, v1 = acc1 * inv;
  if (DO_RELU){ v0 = fmaxf(v0, 0.f); v1 = fmaxf(v1, 0.f); }
  if (OUT_BF16){
    unsigned pw = (unsigned)f2bf(v0) | ((unsigned)f2bf(v1) << 16);
    ((unsigned*)outbuf)[(size_t)s * 64 + lane] = pw;
  } else {
    ((float2*)outbuf)[(size_t)s * 64 + lane] = make_float2(v0, v1);
  }
}

extern "C" void kernel_launch(void* const* d_in, const int* in_sizes, int n_in,
                              void* d_out, int out_size, void* d_ws, size_t ws_size,
                              hipStream_t stream){
  const float* X      = (const float*)d_in[0];
  const float* W      = (const float*)d_in[1];
  const float* att_e  = (const float*)d_in[2];
  const float* att_v  = (const float*)d_in[3];
  const int*   vertex = (const int*)d_in[4];
  const int*   edges  = (const int*)d_in[5];
  const int*   vtype  = (const int*)d_in[6];
  const int*   etype  = (const int*)d_in[7];
  float* out = (float*)d_out;
  const int N   = in_sizes[0] / 128;
  const int NNZ = in_sizes[4];
  const int E   = in_sizes[7];
  const int S   = E + N;

  // workspace carve
  char* wp = (char*)d_ws;
  int* cnt    = (int*)wp; wp += (size_t)S * 4;        // [0,E) edge, [E,S) vertex
  int* offs   = (int*)wp; wp += (size_t)S * 4;
  int* cursor = (int*)wp; wp += (size_t)S * 4;
  int* bsum   = (int*)wp; wp += 1024;                 // up to 256 block sums
  int* rows   = (int*)wp; wp += (size_t)2 * NNZ * 4;  // [0,NNZ) edge-grouped, [NNZ,2NNZ) vtx-grouped
  unsigned short* X0 = (unsigned short*)wp; wp += (size_t)N * 128 * 2;
  unsigned short* Xe = (unsigned short*)wp; wp += (size_t)E * 128 * 2;
  short* Bfrag = (short*)wp; wp += (size_t)65536 * 2;

  hipMemsetAsync(cnt, 0, (size_t)S * 4, stream);

  // typed projection
  k_bprep<<<256, 256, 0, stream>>>(W, Bfrag);
  k_gemm<<<(N + 63) / 64, 256, 0, stream>>>(X, vtype, Bfrag, X0, N);

  // unified CSR build
  const int nbI = (NNZ + 255) / 256;
  const int nbS = (S + 1023) / 1024;
  k_hist2<<<nbI, 256, 0, stream>>>(edges, vertex, NNZ, cnt, E);
  k_scanA<<<nbS, 256, 0, stream>>>(cnt, S, bsum);
  k_scanB<<<1, 64, 0, stream>>>(bsum, nbS);
  k_scanC<<<nbS, 256, 0, stream>>>(cnt, S, bsum, offs, cursor);
  k_place2<<<nbI, 256, 0, stream>>>(edges, vertex, NNZ, cursor, rows, E);

  // phase 1: vertex -> edge (relu, bf16 out); phase 2: edge -> vertex (fp32 out)
  k_seg<1, 1><<<(E + 3) / 4, 256, 0, stream>>>((const unsigned*)X0, att_e, rows,
                                               offs, cnt, etype, Xe, E);
  k_seg<0, 0><<<(N + 3) / 4, 256, 0, stream>>>((const unsigned*)Xe, att_v, rows,
                                               offs + E, cnt + E, vtype, out, N);
}

// Round 5
// 472.353 us; speedup vs baseline: 6.3595x; 1.0968x over previous
//
#include <hip/hip_runtime.h>

typedef __attribute__((ext_vector_type(8))) short bf16x8;
typedef __attribute__((ext_vector_type(4))) float f32x4;

#define NEG_SLOPE 0.2f

__device__ __forceinline__ unsigned short f2bf(float f){
  unsigned u = __float_as_uint(f);
  u = (u + 0x7fffu + ((u >> 16) & 1u)) >> 16;   // RNE
  return (unsigned short)u;
}
__device__ __forceinline__ float bflo(unsigned u){ return __uint_as_float(u << 16); }
__device__ __forceinline__ float bfhi(unsigned u){ return __uint_as_float(u & 0xffff0000u); }

// ---------------------------------------------------------------------------
// K0: pack W_typed fp32 [4,128,128] -> bf16 in MFMA B-fragment order.
// ---------------------------------------------------------------------------
__global__ __launch_bounds__(256) void k_bprep(const float* __restrict__ W,
                                               short* __restrict__ Bfrag){
  int u = blockIdx.x * 256 + threadIdx.x;          // 0..65535
  int j = u & 7, lane = (u >> 3) & 63, ct = (u >> 9) & 31, ks = u >> 14;
  int k = ks * 32 + ((lane >> 4) << 3) + j;
  int col = (ct << 4) + (lane & 15);
  int t = col >> 7, o = col & 127;
  Bfrag[u] = (short)f2bf(W[(t * 128 + k) * 128 + o]);
}

// ---------------------------------------------------------------------------
// F1: fused [hist2 | gemm].  Blocks [0, nbHist) do the CSR histogram
// (latency-bound atomics); blocks [nbHist, nbHist+nbGemm) do the typed
// projection (compute-bound MFMA). Independent work, co-resident.
// ---------------------------------------------------------------------------
__global__ __launch_bounds__(256, 2) void k_gemm_hist(const float* __restrict__ X,
    const int* __restrict__ vtype, const short* __restrict__ Bfrag,
    unsigned short* __restrict__ X0, int N,
    const int* __restrict__ edges, const int* __restrict__ vertex, int NNZ,
    int* __restrict__ cnt, int E, int nbHist){
  __shared__ short shB[32 * 64 * 8];               // 32KB (gemm branch only)
  const int tid = threadIdx.x;

  if ((int)blockIdx.x < nbHist){
    int i = blockIdx.x * 256 + tid;
    if (i < NNZ){
      atomicAdd(cnt + edges[i], 1);
      atomicAdd(cnt + E + vertex[i], 1);
    }
    return;
  }

  const int w = tid >> 6, lane = tid & 63;
  const int blockRow = ((int)blockIdx.x - nbHist) * 64;
  const int m = lane & 15, q = lane >> 4;
  const int node = blockRow + w * 16 + m;

  bf16x8 afrag[4];
  #pragma unroll
  for (int ks = 0; ks < 4; ++ks){
    bf16x8 f;
    if (node < N){
      const float4* src = (const float4*)(X + (size_t)node * 128 + ks * 32 + q * 8);
      float4 a = src[0], b = src[1];
      f[0]=(short)f2bf(a.x); f[1]=(short)f2bf(a.y); f[2]=(short)f2bf(a.z); f[3]=(short)f2bf(a.w);
      f[4]=(short)f2bf(b.x); f[5]=(short)f2bf(b.y); f[6]=(short)f2bf(b.z); f[7]=(short)f2bf(b.w);
    } else {
      #pragma unroll
      for (int z = 0; z < 8; ++z) f[z] = 0;
    }
    afrag[ks] = f;
  }

  f32x4 acc[32];
  #pragma unroll
  for (int ct = 0; ct < 32; ++ct){
    acc[ct][0]=0.f; acc[ct][1]=0.f; acc[ct][2]=0.f; acc[ct][3]=0.f;
  }

  for (int ks = 0; ks < 4; ++ks){
    __syncthreads();
    const bf16x8* src = (const bf16x8*)(Bfrag + (((size_t)ks * 32 + w * 8) * 64 + lane) * 8);
    bf16x8* dst = (bf16x8*)(shB + ((w * 8) * 64 + lane) * 8);
    #pragma unroll
    for (int ci = 0; ci < 8; ++ci) dst[ci * 64] = src[ci * 64];
    __syncthreads();
    bf16x8 af = afrag[ks];
    #pragma unroll
    for (int ct = 0; ct < 32; ++ct){
      bf16x8 bf = *(const bf16x8*)(shB + (ct * 64 + lane) * 8);
      acc[ct] = __builtin_amdgcn_mfma_f32_16x16x32_bf16(af, bf, acc[ct], 0, 0, 0);
    }
  }

  const int col0 = lane & 15;
  #pragma unroll
  for (int r = 0; r < 4; ++r){
    int noder = blockRow + w * 16 + q * 4 + r;
    if (noder >= N) continue;
    int tt = vtype[noder];
    #pragma unroll
    for (int ct = 0; ct < 32; ++ct){
      if ((ct >> 3) == tt)
        X0[(size_t)noder * 128 + (ct & 7) * 16 + col0] = f2bf(acc[ct][r]);
    }
  }
}

// ---------------------------------------------------------------------------
// Prefix scan over cnt -> offs (+cursor copy)
// ---------------------------------------------------------------------------
__global__ __launch_bounds__(256) void k_scanA(const int* __restrict__ cnt, int S,
                                               int* __restrict__ bsum){
  __shared__ int sh[256];
  int base = blockIdx.x * 1024 + threadIdx.x * 4;
  int s = 0;
  #pragma unroll
  for (int k = 0; k < 4; ++k){ int idx = base + k; if (idx < S) s += cnt[idx]; }
  sh[threadIdx.x] = s; __syncthreads();
  for (int off = 128; off > 0; off >>= 1){
    if (threadIdx.x < off) sh[threadIdx.x] += sh[threadIdx.x + off];
    __syncthreads();
  }
  if (threadIdx.x == 0) bsum[blockIdx.x] = sh[0];
}

__global__ void k_scanB(int* bsum, int nb){
  if (threadIdx.x == 0 && blockIdx.x == 0){
    int run = 0;
    for (int b = 0; b < nb; ++b){ int v = bsum[b]; bsum[b] = run; run += v; }
  }
}

__global__ __launch_bounds__(256) void k_scanC(const int* __restrict__ cnt, int S,
    const int* __restrict__ bsum, int* __restrict__ offs, int* __restrict__ cursor){
  __shared__ int sh[256];
  int t = threadIdx.x;
  int base = blockIdx.x * 1024 + t * 4;
  int c[4]; int s = 0;
  #pragma unroll
  for (int k = 0; k < 4; ++k){ int idx = base + k; c[k] = (idx < S) ? cnt[idx] : 0; s += c[k]; }
  sh[t] = s; __syncthreads();
  for (int off = 1; off < 256; off <<= 1){
    int v = (t >= off) ? sh[t - off] : 0; __syncthreads();
    sh[t] += v; __syncthreads();
  }
  int run = bsum[blockIdx.x] + sh[t] - s;           // exclusive prefix for this thread
  #pragma unroll
  for (int k = 0; k < 4; ++k){
    int idx = base + k;
    if (idx < S){ offs[idx] = run; cursor[idx] = run; run += c[k]; }
  }
}

// ---------------------------------------------------------------------------
// place (edge side): rows[pos] = vertex[i] grouped by edges[i].
// Store via atomicExch: executes in TCC, line accumulates in L2 (avoids
// masked partial-line write streaming -> write amplification).
// ---------------------------------------------------------------------------
__global__ __launch_bounds__(256) void k_place_e(const int* __restrict__ edges,
    const int* __restrict__ vertex, int nnz, int* __restrict__ cursor,
    int* __restrict__ rows){
  int i = blockIdx.x * 256 + threadIdx.x;
  if (i < nnz){
    int pos = atomicAdd(cursor + edges[i], 1);
    atomicExch(rows + pos, vertex[i]);
  }
}

// ---------------------------------------------------------------------------
// seg_body: fused attention + softmax + weighted segment-sum. One wave/segment.
// Member indices loaded cooperatively 64/chunk (one coalesced load), broadcast
// via shfl; 4-deep feature-row prefetch pipeline.
// Lane l owns output elems [2l, 2l+1]; head h = l>>3.
// NOTE: offs/cnt hold GLOBAL positions into the unified rows buffer — callers
// must pass the BASE rows pointer (R4 bug: passing rows+NNZ double-offset).
// ---------------------------------------------------------------------------
template<int OUT_BF16, int DO_RELU>
__device__ __forceinline__ void seg_body(const unsigned* __restrict__ feat,
    const float* __restrict__ att, const int* __restrict__ rows_sorted,
    const int* __restrict__ offs, const int* __restrict__ cnt,
    const int* __restrict__ stype, void* __restrict__ outbuf,
    int S, int blockId, int tid){
  int wid = tid >> 6, lane = tid & 63;
  int s = blockId * 4 + wid;
  if (s >= S) return;
  int t = stype[s];
  float a0 = att[t * 128 + 2 * lane], a1 = att[t * 128 + 2 * lane + 1];
  int start = offs[s], len = cnt[s];
  float denom = 0.f, acc0 = 0.f, acc1 = 0.f;

  for (int base = 0; base < len; base += 64){
    int m = len - base; if (m > 64) m = 64;
    int idx = 0;
    if (lane < m) idx = rows_sorted[start + base + lane];

    unsigned u0 = 0, u1 = 0, u2 = 0, u3 = 0;
    {
      int r;
      r = __shfl(idx, 0); if (0 < m) u0 = feat[(size_t)r * 64 + lane];
      r = __shfl(idx, 1); if (1 < m) u1 = feat[(size_t)r * 64 + lane];
      r = __shfl(idx, 2); if (2 < m) u2 = feat[(size_t)r * 64 + lane];
      r = __shfl(idx, 3); if (3 < m) u3 = feat[(size_t)r * 64 + lane];
    }
    for (int j = 0; j < m; ++j){
      unsigned uc = u0; u0 = u1; u1 = u2; u2 = u3;
      int jn = j + 4;
      if (jn < m){
        int rn = __shfl(idx, jn);
        u3 = feat[(size_t)rn * 64 + lane];
      }
      float x0 = bflo(uc), x1 = bfhi(uc);
      float p = x0 * a0 + x1 * a1;
      p += __shfl_xor(p, 1);
      p += __shfl_xor(p, 2);
      p += __shfl_xor(p, 4);                        // full 16-elem dot per head
      p = p > 0.f ? p : NEG_SLOPE * p;
      float w = __expf(p);
      denom += w; acc0 += w * x0; acc1 += w * x1;
    }
  }
  float inv = 1.f / (denom + 1e-16f);
  float v0 = acc0 * inv, v1 = acc1 * inv;
  if (DO_RELU){ v0 = fmaxf(v0, 0.f); v1 = fmaxf(v1, 0.f); }
  if (OUT_BF16){
    unsigned pw = (unsigned)f2bf(v0) | ((unsigned)f2bf(v1) << 16);
    ((unsigned*)outbuf)[(size_t)s * 64 + lane] = pw;
  } else {
    ((float2*)outbuf)[(size_t)s * 64 + lane] = make_float2(v0, v1);
  }
}

// ---------------------------------------------------------------------------
// F2: fused [place_v | seg1]. place blocks first (their transactions queue
// while seg1 blocks compute). Independent: seg1 reads rows[0,NNZ) (edge side,
// already placed); place_v writes rows[NNZ,2NNZ).
// ---------------------------------------------------------------------------
__global__ __launch_bounds__(256) void k_place_seg1(
    const int* __restrict__ edges, const int* __restrict__ vertex, int NNZ,
    int* __restrict__ cursor, int* __restrict__ rows, int E, int nbPlace,
    const unsigned* __restrict__ X0, const float* __restrict__ att_e,
    const int* __restrict__ offs, const int* __restrict__ cnt,
    const int* __restrict__ etype, unsigned* __restrict__ Xe){
  if ((int)blockIdx.x < nbPlace){
    int i = blockIdx.x * 256 + threadIdx.x;
    if (i < NNZ){
      int pos = atomicAdd(cursor + E + vertex[i], 1);
      atomicExch(rows + pos, edges[i]);
    }
    return;
  }
  seg_body<1, 1>(X0, att_e, rows, offs, cnt, etype, Xe, E,
                 (int)blockIdx.x - nbPlace, threadIdx.x);
}

__global__ __launch_bounds__(256) void k_seg2(const unsigned* __restrict__ Xe,
    const float* __restrict__ att_v, const int* __restrict__ rows,
    const int* __restrict__ offs, const int* __restrict__ cnt,
    const int* __restrict__ vtype, float* __restrict__ out, int N){
  seg_body<0, 0>(Xe, att_v, rows, offs, cnt, vtype, out, N,
                 (int)blockIdx.x, threadIdx.x);
}

extern "C" void kernel_launch(void* const* d_in, const int* in_sizes, int n_in,
                              void* d_out, int out_size, void* d_ws, size_t ws_size,
                              hipStream_t stream){
  const float* X      = (const float*)d_in[0];
  const float* W      = (const float*)d_in[1];
  const float* att_e  = (const float*)d_in[2];
  const float* att_v  = (const float*)d_in[3];
  const int*   vertex = (const int*)d_in[4];
  const int*   edges  = (const int*)d_in[5];
  const int*   vtype  = (const int*)d_in[6];
  const int*   etype  = (const int*)d_in[7];
  float* out = (float*)d_out;
  const int N   = in_sizes[0] / 128;
  const int NNZ = in_sizes[4];
  const int E   = in_sizes[7];
  const int S   = E + N;

  // workspace carve
  char* wp = (char*)d_ws;
  int* cnt    = (int*)wp; wp += (size_t)S * 4;        // [0,E) edge, [E,S) vertex
  int* offs   = (int*)wp; wp += (size_t)S * 4;
  int* cursor = (int*)wp; wp += (size_t)S * 4;
  int* bsum   = (int*)wp; wp += 1024;                 // up to 256 block sums
  int* rows   = (int*)wp; wp += (size_t)2 * NNZ * 4;  // [0,NNZ) edge-grouped, [NNZ,2NNZ) vtx-grouped
  unsigned short* X0 = (unsigned short*)wp; wp += (size_t)N * 128 * 2;
  unsigned short* Xe = (unsigned short*)wp; wp += (size_t)E * 128 * 2;
  short* Bfrag = (short*)wp; wp += (size_t)65536 * 2;

  hipMemsetAsync(cnt, 0, (size_t)S * 4, stream);

  const int nbI = (NNZ + 255) / 256;                  // 3125
  const int nbG = (N + 63) / 64;                      // 1563
  const int nbS = (S + 1023) / 1024;
  const int nbSeg1 = (E + 3) / 4;

  k_bprep<<<256, 256, 0, stream>>>(W, Bfrag);

  // F1: hist (blocks [0,nbI)) || gemm (blocks [nbI, nbI+nbG))
  k_gemm_hist<<<nbI + nbG, 256, 0, stream>>>(X, vtype, Bfrag,
      (unsigned short*)X0, N, edges, vertex, NNZ, cnt, E, nbI);

  k_scanA<<<nbS, 256, 0, stream>>>(cnt, S, bsum);
  k_scanB<<<1, 64, 0, stream>>>(bsum, nbS);
  k_scanC<<<nbS, 256, 0, stream>>>(cnt, S, bsum, offs, cursor);

  k_place_e<<<nbI, 256, 0, stream>>>(edges, vertex, NNZ, cursor, rows);

  // F2: place_v (blocks [0,nbI)) || seg1 (blocks [nbI, nbI+nbSeg1))
  k_place_seg1<<<nbI + nbSeg1, 256, 0, stream>>>(edges, vertex, NNZ, cursor,
      rows, E, nbI, (const unsigned*)X0, att_e, offs, cnt, etype, (unsigned*)Xe);

  // base rows pointer — offs[E..S) are global positions in [NNZ, 2NNZ)
  k_seg2<<<(N + 3) / 4, 256, 0, stream>>>((const unsigned*)Xe, att_v,
      rows, offs + E, cnt + E, vtype, out, N);
}

// Round 7
// 385.890 us; speedup vs baseline: 7.7845x; 1.2241x over previous
//
#include <hip/hip_runtime.h>

typedef __attribute__((ext_vector_type(8))) short bf16x8;
typedef __attribute__((ext_vector_type(4))) float f32x4;

#define NEG_SLOPE 0.2f

__device__ __forceinline__ unsigned short f2bf(float f){
  unsigned u = __float_as_uint(f);
  u = (u + 0x7fffu + ((u >> 16) & 1u)) >> 16;   // RNE
  return (unsigned short)u;
}
__device__ __forceinline__ float bflo(unsigned u){ return __uint_as_float(u << 16); }
__device__ __forceinline__ float bfhi(unsigned u){ return __uint_as_float(u & 0xffff0000u); }

// ---------------------------------------------------------------------------
// K0: pack W_typed fp32 [4,128,128] -> bf16 in MFMA B-fragment order.
// ---------------------------------------------------------------------------
__global__ __launch_bounds__(256) void k_bprep(const float* __restrict__ W,
                                               short* __restrict__ Bfrag){
  int u = blockIdx.x * 256 + threadIdx.x;          // 0..65535
  int j = u & 7, lane = (u >> 3) & 63, ct = (u >> 9) & 31, ks = u >> 14;
  int k = ks * 32 + ((lane >> 4) << 3) + j;
  int col = (ct << 4) + (lane & 15);
  int t = col >> 7, o = col & 127;
  Bfrag[u] = (short)f2bf(W[(t * 128 + k) * 128 + o]);
}

// ---------------------------------------------------------------------------
// F1: fused [hist2 | gemm], MODULO-interleaved (period 3: roles 0,1 = hist,
// role 2 = gemm) so latency-bound atomic waves and MFMA waves co-reside on
// every CU from the first scheduling round.
// ---------------------------------------------------------------------------
__global__ __launch_bounds__(256, 2) void k_gemm_hist(const float* __restrict__ X,
    const int* __restrict__ vtype, const short* __restrict__ Bfrag,
    unsigned short* __restrict__ X0, int N,
    const int* __restrict__ edges, const int* __restrict__ vertex, int NNZ,
    int* __restrict__ cnt, int E, int nbHist, int nbGemm){
  __shared__ short shB[32 * 64 * 8];               // 32KB (gemm branch only)
  const int tid = threadIdx.x;
  const int q = (int)blockIdx.x / 3, r = (int)blockIdx.x % 3;

  if (r < 2){                                      // hist role
    int hb = 2 * q + r;
    if (hb < nbHist){
      int i = hb * 256 + tid;
      if (i < NNZ){
        atomicAdd(cnt + edges[i], 1);
        atomicAdd(cnt + E + vertex[i], 1);
      }
    }
    return;
  }
  if (q >= nbGemm) return;                         // gemm role

  const int w = tid >> 6, lane = tid & 63;
  const int blockRow = q * 64;
  const int m = lane & 15, qq = lane >> 4;
  const int node = blockRow + w * 16 + m;

  bf16x8 afrag[4];
  #pragma unroll
  for (int ks = 0; ks < 4; ++ks){
    bf16x8 f;
    if (node < N){
      const float4* src = (const float4*)(X + (size_t)node * 128 + ks * 32 + qq * 8);
      float4 a = src[0], b = src[1];
      f[0]=(short)f2bf(a.x); f[1]=(short)f2bf(a.y); f[2]=(short)f2bf(a.z); f[3]=(short)f2bf(a.w);
      f[4]=(short)f2bf(b.x); f[5]=(short)f2bf(b.y); f[6]=(short)f2bf(b.z); f[7]=(short)f2bf(b.w);
    } else {
      #pragma unroll
      for (int z = 0; z < 8; ++z) f[z] = 0;
    }
    afrag[ks] = f;
  }

  f32x4 acc[32];
  #pragma unroll
  for (int ct = 0; ct < 32; ++ct){
    acc[ct][0]=0.f; acc[ct][1]=0.f; acc[ct][2]=0.f; acc[ct][3]=0.f;
  }

  for (int ks = 0; ks < 4; ++ks){
    __syncthreads();
    const bf16x8* src = (const bf16x8*)(Bfrag + (((size_t)ks * 32 + w * 8) * 64 + lane) * 8);
    bf16x8* dst = (bf16x8*)(shB + ((w * 8) * 64 + lane) * 8);
    #pragma unroll
    for (int ci = 0; ci < 8; ++ci) dst[ci * 64] = src[ci * 64];
    __syncthreads();
    bf16x8 af = afrag[ks];
    #pragma unroll
    for (int ct = 0; ct < 32; ++ct){
      bf16x8 bf = *(const bf16x8*)(shB + (ct * 64 + lane) * 8);
      acc[ct] = __builtin_amdgcn_mfma_f32_16x16x32_bf16(af, bf, acc[ct], 0, 0, 0);
    }
  }

  const int col0 = lane & 15;
  #pragma unroll
  for (int rr = 0; rr < 4; ++rr){
    int noder = blockRow + w * 16 + qq * 4 + rr;
    if (noder >= N) continue;
    int tt = vtype[noder];
    #pragma unroll
    for (int ct = 0; ct < 32; ++ct){
      if ((ct >> 3) == tt)
        X0[(size_t)noder * 128 + (ct & 7) * 16 + col0] = f2bf(acc[ct][rr]);
    }
  }
}

// ---------------------------------------------------------------------------
// Prefix scan over cnt -> offs (+cursor copy)
// ---------------------------------------------------------------------------
__global__ __launch_bounds__(256) void k_scanA(const int* __restrict__ cnt, int S,
                                               int* __restrict__ bsum){
  __shared__ int sh[256];
  int base = blockIdx.x * 1024 + threadIdx.x * 4;
  int s = 0;
  #pragma unroll
  for (int k = 0; k < 4; ++k){ int idx = base + k; if (idx < S) s += cnt[idx]; }
  sh[threadIdx.x] = s; __syncthreads();
  for (int off = 128; off > 0; off >>= 1){
    if (threadIdx.x < off) sh[threadIdx.x] += sh[threadIdx.x + off];
    __syncthreads();
  }
  if (threadIdx.x == 0) bsum[blockIdx.x] = sh[0];
}

__global__ void k_scanB(int* bsum, int nb){
  if (threadIdx.x == 0 && blockIdx.x == 0){
    int run = 0;
    for (int b = 0; b < nb; ++b){ int v = bsum[b]; bsum[b] = run; run += v; }
  }
}

__global__ __launch_bounds__(256) void k_scanC(const int* __restrict__ cnt, int S,
    const int* __restrict__ bsum, int* __restrict__ offs, int* __restrict__ cursor){
  __shared__ int sh[256];
  int t = threadIdx.x;
  int base = blockIdx.x * 1024 + t * 4;
  int c[4]; int s = 0;
  #pragma unroll
  for (int k = 0; k < 4; ++k){ int idx = base + k; c[k] = (idx < S) ? cnt[idx] : 0; s += c[k]; }
  sh[t] = s; __syncthreads();
  for (int off = 1; off < 256; off <<= 1){
    int v = (t >= off) ? sh[t - off] : 0; __syncthreads();
    sh[t] += v; __syncthreads();
  }
  int run = bsum[blockIdx.x] + sh[t] - s;           // exclusive prefix for this thread
  #pragma unroll
  for (int k = 0; k < 4; ++k){
    int idx = base + k;
    if (idx < S){ offs[idx] = run; cursor[idx] = run; run += c[k]; }
  }
}

// ---------------------------------------------------------------------------
// place (edge side): rows[pos] = vertex[i] grouped by edges[i]. Plain store
// (atomicExch showed no write-amp benefit in R5 counters).
// ---------------------------------------------------------------------------
__global__ __launch_bounds__(256) void k_place_e(const int* __restrict__ edges,
    const int* __restrict__ vertex, int nnz, int* __restrict__ cursor,
    int* __restrict__ rows){
  int i = blockIdx.x * 256 + threadIdx.x;
  if (i < nnz){
    int pos = atomicAdd(cursor + edges[i], 1);
    rows[pos] = vertex[i];
  }
}

// ---------------------------------------------------------------------------
// seg_body (v1, R5-proven math): fused attention + softmax + weighted
// segment-sum. One wave/segment. Member indices loaded cooperatively
// 64/chunk (one coalesced load), broadcast via shfl; 4-deep feature-row
// prefetch pipeline. Lane l owns output elems [2l, 2l+1]; head h = l>>3.
// offs/cnt hold GLOBAL positions into the unified rows buffer — pass BASE rows.
// ---------------------------------------------------------------------------
template<int OUT_BF16, int DO_RELU>
__device__ __forceinline__ void seg_body(const unsigned* __restrict__ feat,
    const float* __restrict__ att, const int* __restrict__ rows_sorted,
    const int* __restrict__ offs, const int* __restrict__ cnt,
    const int* __restrict__ stype, void* __restrict__ outbuf,
    int S, int blockId, int tid){
  int wid = tid >> 6, lane = tid & 63;
  int s = blockId * 4 + wid;
  if (s >= S) return;
  int t = stype[s];
  float a0 = att[t * 128 + 2 * lane], a1 = att[t * 128 + 2 * lane + 1];
  int start = offs[s], len = cnt[s];
  float denom = 0.f, acc0 = 0.f, acc1 = 0.f;

  for (int base = 0; base < len; base += 64){
    int m = len - base; if (m > 64) m = 64;
    int idx = 0;
    if (lane < m) idx = rows_sorted[start + base + lane];

    unsigned u0 = 0, u1 = 0, u2 = 0, u3 = 0;
    {
      int r;
      r = __shfl(idx, 0); if (0 < m) u0 = feat[(size_t)r * 64 + lane];
      r = __shfl(idx, 1); if (1 < m) u1 = feat[(size_t)r * 64 + lane];
      r = __shfl(idx, 2); if (2 < m) u2 = feat[(size_t)r * 64 + lane];
      r = __shfl(idx, 3); if (3 < m) u3 = feat[(size_t)r * 64 + lane];
    }
    for (int j = 0; j < m; ++j){
      unsigned uc = u0; u0 = u1; u1 = u2; u2 = u3;
      int jn = j + 4;
      if (jn < m){
        int rn = __shfl(idx, jn);
        u3 = feat[(size_t)rn * 64 + lane];
      }
      float x0 = bflo(uc), x1 = bfhi(uc);
      float p = x0 * a0 + x1 * a1;
      p += __shfl_xor(p, 1);
      p += __shfl_xor(p, 2);
      p += __shfl_xor(p, 4);                        // full 16-elem dot per head
      p = p > 0.f ? p : NEG_SLOPE * p;
      float w = __expf(p);
      denom += w; acc0 += w * x0; acc1 += w * x1;
    }
  }
  float inv = 1.f / (denom + 1e-16f);
  float v0 = acc0 * inv, v1 = acc1 * inv;
  if (DO_RELU){ v0 = fmaxf(v0, 0.f); v1 = fmaxf(v1, 0.f); }
  if (OUT_BF16){
    unsigned pw = (unsigned)f2bf(v0) | ((unsigned)f2bf(v1) << 16);
    ((unsigned*)outbuf)[(size_t)s * 64 + lane] = pw;
  } else {
    ((float2*)outbuf)[(size_t)s * 64 + lane] = make_float2(v0, v1);
  }
}

// ---------------------------------------------------------------------------
// F2: fused [place_v | seg1], MODULO-interleaved (period 5: role 0 = place,
// roles 1-4 = seg).  place_v writes rows[NNZ,2NNZ); seg1 reads rows[0,NNZ).
// ---------------------------------------------------------------------------
__global__ __launch_bounds__(256) void k_place_seg1(
    const int* __restrict__ edges, const int* __restrict__ vertex, int NNZ,
    int* __restrict__ cursor, int* __restrict__ rows, int E,
    int nbPlace, int nbSeg,
    const unsigned* __restrict__ X0, const float* __restrict__ att_e,
    const int* __restrict__ offs, const int* __restrict__ cnt,
    const int* __restrict__ etype, void* __restrict__ Xe){
  const int q = (int)blockIdx.x / 5, r = (int)blockIdx.x % 5;
  if (r == 0){
    if (q < nbPlace){
      int i = q * 256 + threadIdx.x;
      if (i < NNZ){
        int pos = atomicAdd(cursor + E + vertex[i], 1);
        rows[pos] = edges[i];
      }
    }
    return;
  }
  int segBlk = q * 4 + (r - 1);
  if (segBlk >= nbSeg) return;
  seg_body<1, 1>(X0, att_e, rows, offs, cnt, etype, Xe, E, segBlk, threadIdx.x);
}

__global__ __launch_bounds__(256) void k_seg2(const unsigned* __restrict__ Xe,
    const float* __restrict__ att_v, const int* __restrict__ rows,
    const int* __restrict__ offs, const int* __restrict__ cnt,
    const int* __restrict__ vtype, float* __restrict__ out, int N){
  seg_body<0, 0>(Xe, att_v, rows, offs, cnt, vtype, out, N,
                 (int)blockIdx.x, threadIdx.x);
}

extern "C" void kernel_launch(void* const* d_in, const int* in_sizes, int n_in,
                              void* d_out, int out_size, void* d_ws, size_t ws_size,
                              hipStream_t stream){
  const float* X      = (const float*)d_in[0];
  const float* W      = (const float*)d_in[1];
  const float* att_e  = (const float*)d_in[2];
  const float* att_v  = (const float*)d_in[3];
  const int*   vertex = (const int*)d_in[4];
  const int*   edges  = (const int*)d_in[5];
  const int*   vtype  = (const int*)d_in[6];
  const int*   etype  = (const int*)d_in[7];
  float* out = (float*)d_out;
  const int N   = in_sizes[0] / 128;
  const int NNZ = in_sizes[4];
  const int E   = in_sizes[7];
  const int S   = E + N;

  // workspace carve
  char* wp = (char*)d_ws;
  int* cnt    = (int*)wp; wp += (size_t)S * 4;        // [0,E) edge, [E,S) vertex
  int* offs   = (int*)wp; wp += (size_t)S * 4;
  int* cursor = (int*)wp; wp += (size_t)S * 4;
  int* bsum   = (int*)wp; wp += 1024;                 // up to 256 block sums
  int* rows   = (int*)wp; wp += (size_t)2 * NNZ * 4;  // [0,NNZ) edge-grouped, [NNZ,2NNZ) vtx-grouped
  unsigned short* X0 = (unsigned short*)wp; wp += (size_t)N * 128 * 2;
  unsigned short* Xe = (unsigned short*)wp; wp += (size_t)E * 128 * 2;
  short* Bfrag = (short*)wp; wp += (size_t)65536 * 2;

  hipMemsetAsync(cnt, 0, (size_t)S * 4, stream);

  const int nbI = (NNZ + 255) / 256;                  // 3125 hist/place blocks
  const int nbG = (N + 63) / 64;                      // 1563 gemm blocks
  const int nbS = (S + 1023) / 1024;
  const int nbSeg1 = (E + 3) / 4;                     // 12500 seg1 blocks

  k_bprep<<<256, 256, 0, stream>>>(W, Bfrag);

  // F1 interleaved: period 3 (2 hist : 1 gemm); grid covers both roles
  k_gemm_hist<<<3 * nbG, 256, 0, stream>>>(X, vtype, Bfrag,
      (unsigned short*)X0, N, edges, vertex, NNZ, cnt, E, nbI, nbG);

  k_scanA<<<nbS, 256, 0, stream>>>(cnt, S, bsum);
  k_scanB<<<1, 64, 0, stream>>>(bsum, nbS);
  k_scanC<<<nbS, 256, 0, stream>>>(cnt, S, bsum, offs, cursor);

  k_place_e<<<nbI, 256, 0, stream>>>(edges, vertex, NNZ, cursor, rows);

  // F2 interleaved: period 5 (1 place : 4 seg); 5*nbI = nbI + nbSeg1 exactly
  k_place_seg1<<<5 * nbI, 256, 0, stream>>>(edges, vertex, NNZ, cursor,
      rows, E, nbI, nbSeg1, (const unsigned*)X0, att_e, offs, cnt, etype, Xe);

  // base rows pointer — offs[E..S) are global positions in [NNZ, 2NNZ)
  k_seg2<<<(N + 3) / 4, 256, 0, stream>>>((const unsigned*)Xe, att_v,
      rows, offs + E, cnt + E, vtype, out, N);
}

// Round 8
// 367.677 us; speedup vs baseline: 8.1701x; 1.0495x over previous
//
#include <hip/hip_runtime.h>

typedef __attribute__((ext_vector_type(8))) short bf16x8;
typedef __attribute__((ext_vector_type(4))) float f32x4;

#define NEG_SLOPE 0.2f

__device__ __forceinline__ unsigned short f2bf(float f){
  unsigned u = __float_as_uint(f);
  u = (u + 0x7fffu + ((u >> 16) & 1u)) >> 16;   // RNE
  return (unsigned short)u;
}
__device__ __forceinline__ float bflo(unsigned u){ return __uint_as_float(u << 16); }
__device__ __forceinline__ float bfhi(unsigned u){ return __uint_as_float(u & 0xffff0000u); }

// ---------------------------------------------------------------------------
// K1: fused [hist | bprep]. Blocks [0,nbHist) histogram both segment spaces
// (full occupancy — no fat sibling role). Blocks [nbHist, nbHist+256) pack
// W_typed fp32 -> bf16 MFMA B-fragment order.
// ---------------------------------------------------------------------------
__global__ __launch_bounds__(256) void k_histprep(
    const int* __restrict__ edges, const int* __restrict__ vertex, int NNZ,
    int* __restrict__ cnt, int E, int nbHist,
    const float* __restrict__ W, short* __restrict__ Bfrag){
  if ((int)blockIdx.x < nbHist){
    int i = blockIdx.x * 256 + threadIdx.x;
    if (i < NNZ){
      atomicAdd(cnt + edges[i], 1);
      atomicAdd(cnt + E + vertex[i], 1);
    }
    return;
  }
  int u = ((int)blockIdx.x - nbHist) * 256 + threadIdx.x;   // 0..65535
  int j = u & 7, lane = (u >> 3) & 63, ct = (u >> 9) & 31, ks = u >> 14;
  int k = ks * 32 + ((lane >> 4) << 3) + j;
  int col = (ct << 4) + (lane & 15);
  int t = col >> 7, o = col & 127;
  Bfrag[u] = (short)f2bf(W[(t * 128 + k) * 128 + o]);
}

// ---------------------------------------------------------------------------
// Prefix scan over cnt -> offs (+cursor copy)
// ---------------------------------------------------------------------------
__global__ __launch_bounds__(256) void k_scanA(const int* __restrict__ cnt, int S,
                                               int* __restrict__ bsum){
  __shared__ int sh[256];
  int base = blockIdx.x * 1024 + threadIdx.x * 4;
  int s = 0;
  #pragma unroll
  for (int k = 0; k < 4; ++k){ int idx = base + k; if (idx < S) s += cnt[idx]; }
  sh[threadIdx.x] = s; __syncthreads();
  for (int off = 128; off > 0; off >>= 1){
    if (threadIdx.x < off) sh[threadIdx.x] += sh[threadIdx.x + off];
    __syncthreads();
  }
  if (threadIdx.x == 0) bsum[blockIdx.x] = sh[0];
}

__global__ void k_scanB(int* bsum, int nb){
  if (threadIdx.x == 0 && blockIdx.x == 0){
    int run = 0;
    for (int b = 0; b < nb; ++b){ int v = bsum[b]; bsum[b] = run; run += v; }
  }
}

__global__ __launch_bounds__(256) void k_scanC(const int* __restrict__ cnt, int S,
    const int* __restrict__ bsum, int* __restrict__ offs, int* __restrict__ cursor){
  __shared__ int sh[256];
  int t = threadIdx.x;
  int base = blockIdx.x * 1024 + t * 4;
  int c[4]; int s = 0;
  #pragma unroll
  for (int k = 0; k < 4; ++k){ int idx = base + k; c[k] = (idx < S) ? cnt[idx] : 0; s += c[k]; }
  sh[t] = s; __syncthreads();
  for (int off = 1; off < 256; off <<= 1){
    int v = (t >= off) ? sh[t - off] : 0; __syncthreads();
    sh[t] += v; __syncthreads();
  }
  int run = bsum[blockIdx.x] + sh[t] - s;           // exclusive prefix for this thread
  #pragma unroll
  for (int k = 0; k < 4; ++k){
    int idx = base + k;
    if (idx < S){ offs[idx] = run; cursor[idx] = run; run += c[k]; }
  }
}

// ---------------------------------------------------------------------------
// F_A: fused [gemm | place_e], MODULO-interleaved period 3 (role 0 = gemm,
// roles 1,2 = place_e). gemm is compute/LDS-bound; place_e is atomic-latency
// bound — co-residency hides place_e entirely (R7-verified technique).
// place_e: rows[pos] = vertex[i] grouped by edges[i] (plain store; atomicExch
// showed no write-amp benefit in R5 counters).
// ---------------------------------------------------------------------------
__global__ __launch_bounds__(256, 2) void k_gemm_place(const float* __restrict__ X,
    const int* __restrict__ vtype, const short* __restrict__ Bfrag,
    unsigned short* __restrict__ X0, int N, int nbGemm,
    const int* __restrict__ edges, const int* __restrict__ vertex, int NNZ,
    int* __restrict__ cursor, int* __restrict__ rows, int nbPlace){
  __shared__ short shB[32 * 64 * 8];               // 32KB (gemm branch only)
  const int tid = threadIdx.x;
  const int q = (int)blockIdx.x / 3, r = (int)blockIdx.x % 3;

  if (r != 0){                                     // place_e role
    int hb = 2 * q + (r - 1);
    if (hb < nbPlace){
      int i = hb * 256 + tid;
      if (i < NNZ){
        int pos = atomicAdd(cursor + edges[i], 1);
        rows[pos] = vertex[i];
      }
    }
    return;
  }
  if (q >= nbGemm) return;                         // gemm role

  const int w = tid >> 6, lane = tid & 63;
  const int blockRow = q * 64;
  const int m = lane & 15, qq = lane >> 4;
  const int node = blockRow + w * 16 + m;

  bf16x8 afrag[4];
  #pragma unroll
  for (int ks = 0; ks < 4; ++ks){
    bf16x8 f;
    if (node < N){
      const float4* src = (const float4*)(X + (size_t)node * 128 + ks * 32 + qq * 8);
      float4 a = src[0], b = src[1];
      f[0]=(short)f2bf(a.x); f[1]=(short)f2bf(a.y); f[2]=(short)f2bf(a.z); f[3]=(short)f2bf(a.w);
      f[4]=(short)f2bf(b.x); f[5]=(short)f2bf(b.y); f[6]=(short)f2bf(b.z); f[7]=(short)f2bf(b.w);
    } else {
      #pragma unroll
      for (int z = 0; z < 8; ++z) f[z] = 0;
    }
    afrag[ks] = f;
  }

  f32x4 acc[32];
  #pragma unroll
  for (int ct = 0; ct < 32; ++ct){
    acc[ct][0]=0.f; acc[ct][1]=0.f; acc[ct][2]=0.f; acc[ct][3]=0.f;
  }

  for (int ks = 0; ks < 4; ++ks){
    __syncthreads();
    const bf16x8* src = (const bf16x8*)(Bfrag + (((size_t)ks * 32 + w * 8) * 64 + lane) * 8);
    bf16x8* dst = (bf16x8*)(shB + ((w * 8) * 64 + lane) * 8);
    #pragma unroll
    for (int ci = 0; ci < 8; ++ci) dst[ci * 64] = src[ci * 64];
    __syncthreads();
    bf16x8 af = afrag[ks];
    #pragma unroll
    for (int ct = 0; ct < 32; ++ct){
      bf16x8 bf = *(const bf16x8*)(shB + (ct * 64 + lane) * 8);
      acc[ct] = __builtin_amdgcn_mfma_f32_16x16x32_bf16(af, bf, acc[ct], 0, 0, 0);
    }
  }

  const int col0 = lane & 15;
  #pragma unroll
  for (int rr = 0; rr < 4; ++rr){
    int noder = blockRow + w * 16 + qq * 4 + rr;
    if (noder >= N) continue;
    int tt = vtype[noder];
    #pragma unroll
    for (int ct = 0; ct < 32; ++ct){
      if ((ct >> 3) == tt)
        X0[(size_t)noder * 128 + (ct & 7) * 16 + col0] = f2bf(acc[ct][rr]);
    }
  }
}

// ---------------------------------------------------------------------------
// seg_body v1-ILP2: same per-lane topology and FP accumulation order as the
// R5/R7-proven v1, but 2 rows per iteration with INDEPENDENT shfl-reduce
// chains (doubles cross-lane/exp ILP). Lane l owns output elems [2l, 2l+1];
// head h = l>>3; member indices loaded cooperatively 64/chunk and broadcast
// via shfl; 4-row register prefetch pipeline.
// offs/cnt hold GLOBAL positions into the unified rows buffer — pass BASE rows.
// ---------------------------------------------------------------------------
template<int OUT_BF16, int DO_RELU>
__device__ __forceinline__ void seg_body(const unsigned* __restrict__ feat,
    const float* __restrict__ att, const int* __restrict__ rows_sorted,
    const int* __restrict__ offs, const int* __restrict__ cnt,
    const int* __restrict__ stype, void* __restrict__ outbuf,
    int S, int blockId, int tid){
  int wid = tid >> 6, lane = tid & 63;
  int s = blockId * 4 + wid;
  if (s >= S) return;
  int t = stype[s];
  float a0 = att[t * 128 + 2 * lane], a1 = att[t * 128 + 2 * lane + 1];
  int start = offs[s], len = cnt[s];
  float denom = 0.f, acc0 = 0.f, acc1 = 0.f;

  for (int base = 0; base < len; base += 64){
    int m = len - base; if (m > 64) m = 64;
    int idx = 0;
    if (lane < m) idx = rows_sorted[start + base + lane];

    unsigned u0 = 0, u1 = 0, u2 = 0, u3 = 0;
    {
      int r;
      r = __shfl(idx, 0); if (0 < m) u0 = feat[(size_t)r * 64 + lane];
      r = __shfl(idx, 1); if (1 < m) u1 = feat[(size_t)r * 64 + lane];
      r = __shfl(idx, 2); if (2 < m) u2 = feat[(size_t)r * 64 + lane];
      r = __shfl(idx, 3); if (3 < m) u3 = feat[(size_t)r * 64 + lane];
    }
    for (int j = 0; j < m; j += 2){
      unsigned ua = u0, ub = u1;
      u0 = u2; u1 = u3;
      if (j + 4 < m){ int rn = __shfl(idx, j + 4); u2 = feat[(size_t)rn * 64 + lane]; }
      if (j + 5 < m){ int rn = __shfl(idx, j + 5); u3 = feat[(size_t)rn * 64 + lane]; }

      float xa0 = bflo(ua), xa1 = bfhi(ua);
      float xb0 = bflo(ub), xb1 = bfhi(ub);
      float pa = xa0 * a0 + xa1 * a1;
      float pb = xb0 * a0 + xb1 * a1;
      pa += __shfl_xor(pa, 1);  pb += __shfl_xor(pb, 1);
      pa += __shfl_xor(pa, 2);  pb += __shfl_xor(pb, 2);
      pa += __shfl_xor(pa, 4);  pb += __shfl_xor(pb, 4);
      pa = pa > 0.f ? pa : NEG_SLOPE * pa;
      float wa = __expf(pa);
      denom += wa; acc0 += wa * xa0; acc1 += wa * xa1;
      if (j + 1 < m){
        pb = pb > 0.f ? pb : NEG_SLOPE * pb;
        float wb = __expf(pb);
        denom += wb; acc0 += wb * xb0; acc1 += wb * xb1;
      }
    }
  }
  float inv = 1.f / (denom + 1e-16f);
  float v0 = acc0 * inv, v1 = acc1 * inv;
  if (DO_RELU){ v0 = fmaxf(v0, 0.f); v1 = fmaxf(v1, 0.f); }
  if (OUT_BF16){
    unsigned pw = (unsigned)f2bf(v0) | ((unsigned)f2bf(v1) << 16);
    ((unsigned*)outbuf)[(size_t)s * 64 + lane] = pw;
  } else {
    ((float2*)outbuf)[(size_t)s * 64 + lane] = make_float2(v0, v1);
  }
}

// ---------------------------------------------------------------------------
// F_B: fused [place_v | seg1], MODULO-interleaved period 5 (role 0 = place,
// roles 1-4 = seg).  place_v writes rows[NNZ,2NNZ); seg1 reads rows[0,NNZ).
// ---------------------------------------------------------------------------
__global__ __launch_bounds__(256) void k_place_seg1(
    const int* __restrict__ edges, const int* __restrict__ vertex, int NNZ,
    int* __restrict__ cursor, int* __restrict__ rows, int E,
    int nbPlace, int nbSeg,
    const unsigned* __restrict__ X0, const float* __restrict__ att_e,
    const int* __restrict__ offs, const int* __restrict__ cnt,
    const int* __restrict__ etype, void* __restrict__ Xe){
  const int q = (int)blockIdx.x / 5, r = (int)blockIdx.x % 5;
  if (r == 0){
    if (q < nbPlace){
      int i = q * 256 + threadIdx.x;
      if (i < NNZ){
        int pos = atomicAdd(cursor + E + vertex[i], 1);
        rows[pos] = edges[i];
      }
    }
    return;
  }
  int segBlk = q * 4 + (r - 1);
  if (segBlk >= nbSeg) return;
  seg_body<1, 1>(X0, att_e, rows, offs, cnt, etype, Xe, E, segBlk, threadIdx.x);
}

__global__ __launch_bounds__(256) void k_seg2(const unsigned* __restrict__ Xe,
    const float* __restrict__ att_v, const int* __restrict__ rows,
    const int* __restrict__ offs, const int* __restrict__ cnt,
    const int* __restrict__ vtype, float* __restrict__ out, int N){
  seg_body<0, 0>(Xe, att_v, rows, offs, cnt, vtype, out, N,
                 (int)blockIdx.x, threadIdx.x);
}

extern "C" void kernel_launch(void* const* d_in, const int* in_sizes, int n_in,
                              void* d_out, int out_size, void* d_ws, size_t ws_size,
                              hipStream_t stream){
  const float* X      = (const float*)d_in[0];
  const float* W      = (const float*)d_in[1];
  const float* att_e  = (const float*)d_in[2];
  const float* att_v  = (const float*)d_in[3];
  const int*   vertex = (const int*)d_in[4];
  const int*   edges  = (const int*)d_in[5];
  const int*   vtype  = (const int*)d_in[6];
  const int*   etype  = (const int*)d_in[7];
  float* out = (float*)d_out;
  const int N   = in_sizes[0] / 128;
  const int NNZ = in_sizes[4];
  const int E   = in_sizes[7];
  const int S   = E + N;

  // workspace carve
  char* wp = (char*)d_ws;
  int* cnt    = (int*)wp; wp += (size_t)S * 4;        // [0,E) edge, [E,S) vertex
  int* offs   = (int*)wp; wp += (size_t)S * 4;
  int* cursor = (int*)wp; wp += (size_t)S * 4;
  int* bsum   = (int*)wp; wp += 1024;                 // up to 256 block sums
  int* rows   = (int*)wp; wp += (size_t)2 * NNZ * 4;  // [0,NNZ) edge-grouped, [NNZ,2NNZ) vtx-grouped
  unsigned short* X0 = (unsigned short*)wp; wp += (size_t)N * 128 * 2;
  unsigned short* Xe = (unsigned short*)wp; wp += (size_t)E * 128 * 2;
  short* Bfrag = (short*)wp; wp += (size_t)65536 * 2;

  hipMemsetAsync(cnt, 0, (size_t)S * 4, stream);

  const int nbI = (NNZ + 255) / 256;                  // 3125 hist/place blocks
  const int nbG = (N + 63) / 64;                      // 1563 gemm blocks
  const int nbS = (S + 1023) / 1024;
  const int nbSeg1 = (E + 3) / 4;                     // 12500 seg1 blocks

  // hist (full occupancy) + bprep appended
  k_histprep<<<nbI + 256, 256, 0, stream>>>(edges, vertex, NNZ, cnt, E, nbI,
                                            W, Bfrag);

  k_scanA<<<nbS, 256, 0, stream>>>(cnt, S, bsum);
  k_scanB<<<1, 64, 0, stream>>>(bsum, nbS);
  k_scanC<<<nbS, 256, 0, stream>>>(cnt, S, bsum, offs, cursor);

  // F_A interleaved: period 3 (1 gemm : 2 place_e); 2*nbG*256 >= NNZ coverage
  k_gemm_place<<<3 * nbG, 256, 0, stream>>>(X, vtype, Bfrag,
      (unsigned short*)X0, N, nbG, edges, vertex, NNZ, cursor, rows, nbI);

  // F_B interleaved: period 5 (1 place_v : 4 seg1); 5*nbI = nbI + nbSeg1
  k_place_seg1<<<5 * nbI, 256, 0, stream>>>(edges, vertex, NNZ, cursor,
      rows, E, nbI, nbSeg1, (const unsigned*)X0, att_e, offs, cnt, etype, Xe);

  // base rows pointer — offs[E..S) are global positions in [NNZ, 2NNZ)
  k_seg2<<<(N + 3) / 4, 256, 0, stream>>>((const unsigned*)Xe, att_v,
      rows, offs + E, cnt + E, vtype, out, N);
}